// Round 9
// baseline (55045.728 us; speedup 1.0000x reference)
//
#include <hip/hip_runtime.h>

// Problem constants
#define Bc   64
#define Tc   512
#define NINc 256
#define Hc   512
#define NOUTc 256
#define NBLK 256
#define NTHR 1024
#define NWAVE 16
#define GSZ  32      // blocks per barrier group
#define NGRP 8       // groups

__device__ __forceinline__ double dsig(double x) { return 1.0 / (1.0 + exp(-x)); }

// ---- tree-counter grid barrier ----
// arrival (tid0 only): release-fence (ONE wbl2/block), relaxed RMW on the group
// counter (8 lines in parallel, 32-way serial each); last group arriver RMWs the
// root; last root arriver publishes go=ep. Monotone counters, no resets.
__device__ __forceinline__ void bar_arrive(unsigned* __restrict__ grp,
                                           unsigned* __restrict__ root,
                                           unsigned* __restrict__ go,
                                           int blk, unsigned ep) {
  __syncthreads();   // all waves' stores drained to L2 (vmcnt0 before s_barrier)
  if (threadIdx.x == 0) {
    __builtin_amdgcn_fence(__ATOMIC_RELEASE, "agent");   // wbl2: publish dirty lines
    unsigned old = __hip_atomic_fetch_add(&grp[(blk >> 5) * 32], 1u,
                                          __ATOMIC_RELAXED, __HIP_MEMORY_SCOPE_AGENT);
    if (old == ep * GSZ - 1) {
      unsigned rold = __hip_atomic_fetch_add(root, 1u,
                                             __ATOMIC_RELAXED, __HIP_MEMORY_SCOPE_AGENT);
      if (rold == ep * NGRP - 1)
        __hip_atomic_store(go, ep, __ATOMIC_RELAXED, __HIP_MEMORY_SCOPE_AGENT);
    }
  }
}
// wait (tid0 polls ONE word; ONE inv/block), then block-wide sync.
__device__ __forceinline__ void bar_wait(unsigned* __restrict__ go, unsigned ep) {
  if (threadIdx.x == 0) {
    while (__hip_atomic_load(go, __ATOMIC_RELAXED, __HIP_MEMORY_SCOPE_AGENT) < ep)
      __builtin_amdgcn_s_sleep(2);
    __builtin_amdgcn_fence(__ATOMIC_ACQUIRE, "agent");   // inv: drop stale clean lines
  }
  __syncthreads();
  asm volatile("" ::: "memory");
}

// ---- 8-row dot chunk, A strided by Bc (activations, normal cached loads) ----
// mixed precision: 4-term f32 fma groups summed into f64 accumulators
template<int NK>
__device__ __forceinline__ void dot8_a(const float* __restrict__ A,
                                       const float* __restrict__ W,
                                       const int wstride,
                                       double* __restrict__ acc) {
  float av[NK];
#pragma unroll
  for (int k = 0; k < NK; ++k) av[k] = A[k * Bc];
#pragma unroll
  for (int kk = 0; kk < NK; kk += 4) {
#pragma unroll
    for (int r = 0; r < 8; ++r) {
      float4 w = *(const float4*)(W + r * wstride + kk);
      float p =  av[kk + 0] * w.x;
      p = fmaf(av[kk + 1], w.y, p);
      p = fmaf(av[kk + 2], w.z, p);
      p = fmaf(av[kk + 3], w.w, p);
      acc[r] += (double)p;
    }
  }
}

// Same but A contiguous (raw x row, cached)
template<int NK>
__device__ __forceinline__ void dot8_x(const float* __restrict__ A,
                                       const float* __restrict__ W,
                                       const int wstride,
                                       double* __restrict__ acc) {
#pragma unroll
  for (int kk = 0; kk < NK; kk += 4) {
    float4 av = *(const float4*)(A + kk);
#pragma unroll
    for (int r = 0; r < 8; ++r) {
      float4 w = *(const float4*)(W + r * wstride + kk);
      float p =  av.x * w.x;
      p = fmaf(av.y, w.y, p);
      p = fmaf(av.z, w.z, p);
      p = fmaf(av.w, w.w, p);
      acc[r] += (double)p;
    }
  }
}

__device__ __forceinline__ void write_plane(float* __restrict__ pb,
                                            const double* __restrict__ acc,
                                            int kg, int b) {
#pragma unroll
  for (int r = 0; r < 8; ++r) pb[(kg * 8 + r) * 64 + b] = (float)acc[r];
}

__device__ __forceinline__ double sum_planes(const float* __restrict__ pb,
                                             int r, int b) {
  double s = 0.0;
#pragma unroll
  for (int p = 0; p < NWAVE; ++p) s += (double)pb[(p * 8 + r) * 64 + b];
  return s;
}

__device__ __forceinline__ float lstm_cell(const float* __restrict__ pb,
                                           const double* __restrict__ bias,
                                           int r0, int b, double* c) {
  double gi = sum_planes(pb, r0 + 0, b) + bias[r0 + 0];
  double gf = sum_planes(pb, r0 + 1, b) + bias[r0 + 1];
  double gg = sum_planes(pb, r0 + 2, b) + bias[r0 + 2];
  double go = sum_planes(pb, r0 + 3, b) + bias[r0 + 3];
  double cn = dsig(gf) * (*c) + dsig(gi) * tanh(gg);
  *c = cn;
  return (float)(dsig(go) * tanh(cn));
}

extern "C" __global__ __launch_bounds__(NTHR, 1)
void lstm_seq_kernel(const float* __restrict__ x,      // [B,T,NIN]
                     const float* __restrict__ h0in,   // [L,B,H]
                     const float* __restrict__ c0in,   // [L,B,H]
                     const float* __restrict__ Wih0,   // [4H,NIN]
                     const float* __restrict__ Wih1,   // [4H,H]
                     const float* __restrict__ Whh,    // [L,4H,H]
                     const float* __restrict__ bih,    // [L,4H]
                     const float* __restrict__ bhh,    // [L,4H]
                     const float* __restrict__ Wemb,   // [NOUT,H]
                     const float* __restrict__ bemb,   // [NOUT]
                     const unsigned char* __restrict__ uprev, // [T] bool (or int32)
                     float* __restrict__ out,          // [B,T,NOUT]
                     float* __restrict__ ws) {
  __shared__ __align__(16) float wl0[8 * 768];    // [r][ W_ih0(256) | W_hh0(512) ]
  __shared__ __align__(16) float wl1[8 * 1024];   // [r][ W_ih1(512) | W_hh1(512) ]
  __shared__ __align__(16) float whd[512];        // W_emb row `blk`
  __shared__ __align__(16) float pbuf[NWAVE * 8 * 64];
  __shared__ double biasesD[2][8];
  __shared__ double bembs;
  __shared__ int up_mode;

  const int tid = threadIdx.x;
  const int blk = blockIdx.x;
  const int b   = tid & 63;
  const int kg  = tid >> 6;   // wave index = K-group (0..15)
  const int j0  = blk * 2;

  // ---- workspace map (first 4 KiB control, zeroed by host memset) ----
  unsigned* grp  = (unsigned*)ws;              // 8 counters, 128B apart
  unsigned* root = grp + 256;                  // root counter (own line)
  unsigned* go   = grp + 384;                  // go epoch word (own line)
  float* hbuf = ws + 1024;                     // [2 parity][L][H][B]
  float* outT = hbuf + 2 * 2 * Hc * Bc;        // [NOUT][B]

  // ---- detect use_prev dtype ----
  if (tid == 0) up_mode = 1;
  __syncthreads();
  {
    int bad = 0;
    for (int idx = tid; idx < Tc; idx += NTHR)
      if ((idx & 3) && uprev[idx]) bad = 1;
    if (bad) up_mode = 0;
  }

  // ---- load weights into LDS (cached reads) ----
  for (int r = 0; r < 8; ++r) {
    const int u = r >> 2, g = r & 3;
    const int row = g * Hc + (j0 + u);
    const float* sA = Wih0 + (size_t)row * NINc;
    const float* sB = Whh  + (size_t)row * Hc;
    const float* sC = Wih1 + (size_t)row * Hc;
    const float* sD = Whh  + (size_t)(4 * Hc) * Hc + (size_t)row * Hc;
    for (int i = tid; i < NINc; i += NTHR) wl0[r * 768 + i] = sA[i];
    for (int i = tid; i < Hc;   i += NTHR) wl0[r * 768 + NINc + i] = sB[i];
    for (int i = tid; i < Hc;   i += NTHR) wl1[r * 1024 + i] = sC[i];
    for (int i = tid; i < Hc;   i += NTHR) wl1[r * 1024 + Hc + i] = sD[i];
    if (tid == 0) {
      biasesD[0][r] = (double)bih[row] + (double)bhh[row];
      biasesD[1][r] = (double)bih[4 * Hc + row] + (double)bhh[4 * Hc + row];
    }
  }
  for (int i = tid; i < Hc; i += NTHR) whd[i] = Wemb[(size_t)blk * Hc + i];
  if (tid == 0) bembs = (double)bemb[blk];

  // ---- init h (parity 0) transposed to [L][H][B]; normal stores ----
  for (int idx = blk * NTHR + tid; idx < 2 * Hc * Bc; idx += NBLK * NTHR) {
    const int l   = idx / (Hc * Bc);
    const int rem = idx - l * (Hc * Bc);
    const int j   = rem >> 6;
    const int bb  = rem & 63;
    hbuf[idx] = h0in[((size_t)l * Bc + bb) * Hc + j];
  }

  // ---- cell state (f64) in registers of threads 0..127 ----
  double c0r = 0.0, c1r = 0.0;
  const int cu = tid >> 6;
  if (tid < 128) {
    const int j = j0 + cu;
    c0r = (double)c0in[((size_t)0 * Bc + b) * Hc + j];
    c1r = (double)c0in[((size_t)1 * Bc + b) * Hc + j];
  }
  __syncthreads();
  const int upm = up_mode;
  const int* uprev32 = (const int*)uprev;
#define UPAT(tt) (upm ? (uprev32[tt] != 0) : (uprev[tt] != 0))

  unsigned ep = 0;
  bar_arrive(grp, root, go, blk, ++ep);   // publish hbuf init
  bar_wait(go, ep);

  // ---- pre-loop: L0[0] pre-activation (up[0] false by construction) ----
  double accL0[8];
#pragma unroll
  for (int r = 0; r < 8; ++r) accL0[r] = 0.0;
  dot8_x<16>(x + ((size_t)b * Tc + 0) * NINc + kg * 16, &wl0[kg * 16], 768, accL0);
  dot8_a<32>(hbuf + (kg * 32) * Bc + b, &wl0[NINc + kg * 32], 768, accL0);

  for (int t = 0; t < Tc; ++t) {
    const int p = t & 1;
    const float* hRd = hbuf + p * (2 * Hc * Bc);
    float* hWr = hbuf + (p ^ 1) * (2 * Hc * Bc);
    const bool upn = (t + 1 < Tc) && UPAT(t + 1);

    // ---- phase a: finish L0[t] (out-part only when feedback) ----
    if (t > 0 && UPAT(t))
      dot8_a<16>(outT + (kg * 16) * Bc + b, &wl0[kg * 16], 768, accL0);
    write_plane(pbuf, accL0, kg, b);
    __syncthreads();
    if (tid < 128) {
      float hn = lstm_cell(pbuf, biasesD[0], cu * 4, b, &c0r);
      hWr[(j0 + cu) * Bc + b] = hn;
    }
    bar_arrive(grp, root, go, blk, ++ep);

    // ---- phase b (hidden behind barrier): L1 recurrent part, h1[t-1] (cached) ----
    double acc[8];
#pragma unroll
    for (int r = 0; r < 8; ++r) acc[r] = 0.0;
    dot8_a<32>(hRd + Hc * Bc + (kg * 32) * Bc + b, &wl1[Hc + kg * 32], 1024, acc);

    bar_wait(go, ep);   // h0[t] now visible

    // ---- phase c: L1 dependent part ----
    dot8_a<32>(hWr + (kg * 32) * Bc + b, &wl1[kg * 32], 1024, acc);
    write_plane(pbuf, acc, kg, b);
    __syncthreads();
    if (tid < 128) {
      float hn = lstm_cell(pbuf, biasesD[1], cu * 4, b, &c1r);
      hWr[Hc * Bc + (j0 + cu) * Bc + b] = hn;
    }
    bar_arrive(grp, root, go, blk, ++ep);

    // ---- phase d (hidden behind barrier): precompute L0[t+1] indep parts ----
#pragma unroll
    for (int r = 0; r < 8; ++r) accL0[r] = 0.0;
    if (t + 1 < Tc) {
      if (!upn)
        dot8_x<16>(x + ((size_t)b * Tc + (t + 1)) * NINc + kg * 16, &wl0[kg * 16], 768, accL0);
      dot8_a<32>(hWr + (kg * 32) * Bc + b, &wl0[NINc + kg * 32], 768, accL0); // W_hh0 @ h0[t]
    }

    bar_wait(go, ep);   // h1[t] now visible

    // ---- phase e: head (row n = blk) ----
    {
      const float* Ah = hWr + Hc * Bc + (kg * 32) * Bc + b;
      float av[32];
#pragma unroll
      for (int k = 0; k < 32; ++k) av[k] = Ah[k * Bc];
      double hs = 0.0;
#pragma unroll
      for (int kk = 0; kk < 32; kk += 4) {
        float4 w = *(const float4*)(&whd[kg * 32] + kk);
        float pp =  av[kk + 0] * w.x;
        pp = fmaf(av[kk + 1], w.y, pp);
        pp = fmaf(av[kk + 2], w.z, pp);
        pp = fmaf(av[kk + 3], w.w, pp);
        hs += (double)pp;
      }
      pbuf[kg * 64 + b] = (float)hs;
    }
    __syncthreads();
    if (tid < 64) {
      double s = bembs;
#pragma unroll
      for (int pl = 0; pl < NWAVE; ++pl) s += (double)pbuf[pl * 64 + b];
      float o = (float)tanh(s);
      outT[blk * Bc + b] = o;                          // feedback buffer [NOUT][B]
      out[((size_t)b * Tc + t) * NOUTc + blk] = o;     // final output [B,T,NOUT]
    }
    if (upn) {
      bar_arrive(grp, root, go, blk, ++ep);            // publish out[t]
      bar_wait(go, ep);
    } else if (t + 1 < Tc) {
      __syncthreads();                                 // pbuf reuse guard
    }
  }
}

extern "C" void kernel_launch(void* const* d_in, const int* in_sizes, int n_in,
                              void* d_out, int out_size, void* d_ws, size_t ws_size,
                              hipStream_t stream) {
  const float* x    = (const float*)d_in[0];
  const float* h0   = (const float*)d_in[1];
  const float* c0   = (const float*)d_in[2];
  const float* Wih0 = (const float*)d_in[3];
  const float* Wih1 = (const float*)d_in[4];
  const float* Whh  = (const float*)d_in[5];
  const float* bih  = (const float*)d_in[6];
  const float* bhh  = (const float*)d_in[7];
  const float* Wemb = (const float*)d_in[8];
  const float* bemb = (const float*)d_in[9];
  const unsigned char* uprev = (const unsigned char*)d_in[10];
  float* out = (float*)d_out;
  float* ws  = (float*)d_ws;

  // zero the barrier control region (first 4 KiB) every call (inside graph)
  hipMemsetAsync(d_ws, 0, 4096, stream);

  void* args[] = {(void*)&x, (void*)&h0, (void*)&c0, (void*)&Wih0, (void*)&Wih1,
                  (void*)&Whh, (void*)&bih, (void*)&bhh, (void*)&Wemb, (void*)&bemb,
                  (void*)&uprev, (void*)&out, (void*)&ws};
  hipLaunchCooperativeKernel((void*)lstm_seq_kernel, dim3(NBLK), dim3(NTHR),
                             args, 0, stream);
}

// Round 10
// 16661.386 us; speedup vs baseline: 3.3038x; 3.3038x over previous
//
#include <hip/hip_runtime.h>

// Problem constants
#define Bc   64
#define Tc   512
#define NINc 256
#define Hc   512
#define NOUTc 256
#define NBLK 256
#define NTHR 1024
#define NWAVE 16
#define GSZ  32      // blocks per barrier group
#define NGRP 8       // groups

__device__ __forceinline__ double dsig(double x) { return 1.0 / (1.0 + exp(-x)); }

// ---- tree-counter grid barrier (unchanged from R9) ----
__device__ __forceinline__ void bar_arrive(unsigned* __restrict__ grp,
                                           unsigned* __restrict__ root,
                                           unsigned* __restrict__ go,
                                           int blk, unsigned ep) {
  __syncthreads();   // all waves' stores drained to L2 (vmcnt0 before s_barrier)
  if (threadIdx.x == 0) {
    __builtin_amdgcn_fence(__ATOMIC_RELEASE, "agent");   // wbl2: publish dirty lines
    unsigned old = __hip_atomic_fetch_add(&grp[(blk >> 5) * 32], 1u,
                                          __ATOMIC_RELAXED, __HIP_MEMORY_SCOPE_AGENT);
    if (old == ep * GSZ - 1) {
      unsigned rold = __hip_atomic_fetch_add(root, 1u,
                                             __ATOMIC_RELAXED, __HIP_MEMORY_SCOPE_AGENT);
      if (rold == ep * NGRP - 1)
        __hip_atomic_store(go, ep, __ATOMIC_RELAXED, __HIP_MEMORY_SCOPE_AGENT);
    }
  }
}
__device__ __forceinline__ void bar_wait(unsigned* __restrict__ go, unsigned ep) {
  if (threadIdx.x == 0) {
    while (__hip_atomic_load(go, __ATOMIC_RELAXED, __HIP_MEMORY_SCOPE_AGENT) < ep)
      __builtin_amdgcn_s_sleep(2);
    __builtin_amdgcn_fence(__ATOMIC_ACQUIRE, "agent");   // inv: drop stale clean lines
  }
  __syncthreads();
  asm volatile("" ::: "memory");
}

// ---- 8-row dot chunk, A strided by Bc; SPILL-FREE version ----
// av[16] chunks inside an unroll-1 loop: peak pressure ~50 VGPR (< 64 cap),
// 16 loads in flight per chunk, same summation order as before.
template<int NK>
__device__ __forceinline__ void dot8_a(const float* __restrict__ A,
                                       const float* __restrict__ W,
                                       const int wstride,
                                       double* __restrict__ acc) {
#pragma unroll 1
  for (int c = 0; c < NK / 16; ++c) {
    float av[16];
#pragma unroll
    for (int k = 0; k < 16; ++k) av[k] = A[(c * 16 + k) * Bc];
#pragma unroll
    for (int kk = 0; kk < 16; kk += 4) {
#pragma unroll
      for (int r = 0; r < 8; ++r) {
        float4 w = *(const float4*)(W + r * wstride + c * 16 + kk);
        float p =  av[kk + 0] * w.x;
        p = fmaf(av[kk + 1], w.y, p);
        p = fmaf(av[kk + 2], w.z, p);
        p = fmaf(av[kk + 3], w.w, p);
        acc[r] += (double)p;
      }
    }
  }
}

// A contiguous (raw x row, cached) — float4 loads, low pressure already
template<int NK>
__device__ __forceinline__ void dot8_x(const float* __restrict__ A,
                                       const float* __restrict__ W,
                                       const int wstride,
                                       double* __restrict__ acc) {
#pragma unroll
  for (int kk = 0; kk < NK; kk += 4) {
    float4 av = *(const float4*)(A + kk);
#pragma unroll
    for (int r = 0; r < 8; ++r) {
      float4 w = *(const float4*)(W + r * wstride + kk);
      float p =  av.x * w.x;
      p = fmaf(av.y, w.y, p);
      p = fmaf(av.z, w.z, p);
      p = fmaf(av.w, w.w, p);
      acc[r] += (double)p;
    }
  }
}

__device__ __forceinline__ void write_plane(float* __restrict__ pb,
                                            const double* __restrict__ acc,
                                            int kg, int b) {
#pragma unroll
  for (int r = 0; r < 8; ++r) pb[(kg * 8 + r) * 64 + b] = (float)acc[r];
}

__device__ __forceinline__ double sum_planes(const float* __restrict__ pb,
                                             int r, int b) {
  double s = 0.0;
#pragma unroll
  for (int p = 0; p < NWAVE; ++p) s += (double)pb[(p * 8 + r) * 64 + b];
  return s;
}

__device__ __forceinline__ float lstm_cell(const float* __restrict__ pb,
                                           const double* __restrict__ bias,
                                           int r0, int b, double* c) {
  double gi = sum_planes(pb, r0 + 0, b) + bias[r0 + 0];
  double gf = sum_planes(pb, r0 + 1, b) + bias[r0 + 1];
  double gg = sum_planes(pb, r0 + 2, b) + bias[r0 + 2];
  double go = sum_planes(pb, r0 + 3, b) + bias[r0 + 3];
  double cn = dsig(gf) * (*c) + dsig(gi) * tanh(gg);
  *c = cn;
  return (float)(dsig(go) * tanh(cn));
}

extern "C" __global__ __launch_bounds__(NTHR, 1)
void lstm_seq_kernel(const float* __restrict__ x,      // [B,T,NIN]
                     const float* __restrict__ h0in,   // [L,B,H]
                     const float* __restrict__ c0in,   // [L,B,H]
                     const float* __restrict__ Wih0,   // [4H,NIN]
                     const float* __restrict__ Wih1,   // [4H,H]
                     const float* __restrict__ Whh,    // [L,4H,H]
                     const float* __restrict__ bih,    // [L,4H]
                     const float* __restrict__ bhh,    // [L,4H]
                     const float* __restrict__ Wemb,   // [NOUT,H]
                     const float* __restrict__ bemb,   // [NOUT]
                     const unsigned char* __restrict__ uprev, // [T] bool (or int32)
                     float* __restrict__ out,          // [B,T,NOUT]
                     float* __restrict__ ws) {
  __shared__ __align__(16) float wl0[8 * 768];    // [r][ W_ih0(256) | W_hh0(512) ]
  __shared__ __align__(16) float wl1[8 * 1024];   // [r][ W_ih1(512) | W_hh1(512) ]
  __shared__ __align__(16) float whd[512];        // W_emb row `blk`
  __shared__ __align__(16) float pbuf[NWAVE * 8 * 64];
  __shared__ double biasesD[2][8];
  __shared__ double bembs;
  __shared__ int up_mode;

  const int tid = threadIdx.x;
  const int blk = blockIdx.x;
  const int b   = tid & 63;
  const int kg  = tid >> 6;   // wave index = K-group (0..15)
  const int j0  = blk * 2;

  // ---- workspace map (first 4 KiB control, zeroed by host memset) ----
  unsigned* grp  = (unsigned*)ws;              // 8 counters, 128B apart
  unsigned* root = grp + 256;                  // root counter (own line)
  unsigned* go   = grp + 384;                  // go epoch word (own line)
  float* hbuf = ws + 1024;                     // [2 parity][L][H][B]
  float* outT = hbuf + 2 * 2 * Hc * Bc;        // [NOUT][B]

  // ---- detect use_prev dtype ----
  if (tid == 0) up_mode = 1;
  __syncthreads();
  {
    int bad = 0;
    for (int idx = tid; idx < Tc; idx += NTHR)
      if ((idx & 3) && uprev[idx]) bad = 1;
    if (bad) up_mode = 0;
  }

  // ---- load weights into LDS (cached reads) ----
  for (int r = 0; r < 8; ++r) {
    const int u = r >> 2, g = r & 3;
    const int row = g * Hc + (j0 + u);
    const float* sA = Wih0 + (size_t)row * NINc;
    const float* sB = Whh  + (size_t)row * Hc;
    const float* sC = Wih1 + (size_t)row * Hc;
    const float* sD = Whh  + (size_t)(4 * Hc) * Hc + (size_t)row * Hc;
    for (int i = tid; i < NINc; i += NTHR) wl0[r * 768 + i] = sA[i];
    for (int i = tid; i < Hc;   i += NTHR) wl0[r * 768 + NINc + i] = sB[i];
    for (int i = tid; i < Hc;   i += NTHR) wl1[r * 1024 + i] = sC[i];
    for (int i = tid; i < Hc;   i += NTHR) wl1[r * 1024 + Hc + i] = sD[i];
    if (tid == 0) {
      biasesD[0][r] = (double)bih[row] + (double)bhh[row];
      biasesD[1][r] = (double)bih[4 * Hc + row] + (double)bhh[4 * Hc + row];
    }
  }
  for (int i = tid; i < Hc; i += NTHR) whd[i] = Wemb[(size_t)blk * Hc + i];
  if (tid == 0) bembs = (double)bemb[blk];

  // ---- init h (parity 0) transposed to [L][H][B]; normal stores ----
  for (int idx = blk * NTHR + tid; idx < 2 * Hc * Bc; idx += NBLK * NTHR) {
    const int l   = idx / (Hc * Bc);
    const int rem = idx - l * (Hc * Bc);
    const int j   = rem >> 6;
    const int bb  = rem & 63;
    hbuf[idx] = h0in[((size_t)l * Bc + bb) * Hc + j];
  }

  // ---- cell state (f64) in registers of threads 0..127 ----
  double c0r = 0.0, c1r = 0.0;
  const int cu = tid >> 6;
  if (tid < 128) {
    const int j = j0 + cu;
    c0r = (double)c0in[((size_t)0 * Bc + b) * Hc + j];
    c1r = (double)c0in[((size_t)1 * Bc + b) * Hc + j];
  }
  __syncthreads();
  const int upm = up_mode;
  const int* uprev32 = (const int*)uprev;
#define UPAT(tt) (upm ? (uprev32[tt] != 0) : (uprev[tt] != 0))

  unsigned ep = 0;
  bar_arrive(grp, root, go, blk, ++ep);   // publish hbuf init
  bar_wait(go, ep);

  // ---- pre-loop: L0[0] pre-activation (up[0] false by construction) ----
  double accL0[8];
#pragma unroll
  for (int r = 0; r < 8; ++r) accL0[r] = 0.0;
  dot8_x<16>(x + ((size_t)b * Tc + 0) * NINc + kg * 16, &wl0[kg * 16], 768, accL0);
  dot8_a<32>(hbuf + (kg * 32) * Bc + b, &wl0[NINc + kg * 32], 768, accL0);

  for (int t = 0; t < Tc; ++t) {
    const int p = t & 1;
    const float* hRd = hbuf + p * (2 * Hc * Bc);
    float* hWr = hbuf + (p ^ 1) * (2 * Hc * Bc);
    const bool upn = (t + 1 < Tc) && UPAT(t + 1);

    // ---- phase a: finish L0[t] (out-part only when feedback) ----
    if (t > 0 && UPAT(t))
      dot8_a<16>(outT + (kg * 16) * Bc + b, &wl0[kg * 16], 768, accL0);
    write_plane(pbuf, accL0, kg, b);
    __syncthreads();
    if (tid < 128) {
      float hn = lstm_cell(pbuf, biasesD[0], cu * 4, b, &c0r);
      hWr[(j0 + cu) * Bc + b] = hn;
    }
    bar_arrive(grp, root, go, blk, ++ep);

    // ---- phase b (hidden behind barrier): L1 recurrent part, h1[t-1] (cached) ----
    double acc[8];
#pragma unroll
    for (int r = 0; r < 8; ++r) acc[r] = 0.0;
    dot8_a<32>(hRd + Hc * Bc + (kg * 32) * Bc + b, &wl1[Hc + kg * 32], 1024, acc);

    bar_wait(go, ep);   // h0[t] now visible

    // ---- phase c: L1 dependent part ----
    dot8_a<32>(hWr + (kg * 32) * Bc + b, &wl1[kg * 32], 1024, acc);
    write_plane(pbuf, acc, kg, b);
    __syncthreads();
    if (tid < 128) {
      float hn = lstm_cell(pbuf, biasesD[1], cu * 4, b, &c1r);
      hWr[Hc * Bc + (j0 + cu) * Bc + b] = hn;
    }
    bar_arrive(grp, root, go, blk, ++ep);

    // ---- phase d (hidden behind barrier): precompute L0[t+1] indep parts ----
#pragma unroll
    for (int r = 0; r < 8; ++r) accL0[r] = 0.0;
    if (t + 1 < Tc) {
      if (!upn)
        dot8_x<16>(x + ((size_t)b * Tc + (t + 1)) * NINc + kg * 16, &wl0[kg * 16], 768, accL0);
      dot8_a<32>(hWr + (kg * 32) * Bc + b, &wl0[NINc + kg * 32], 768, accL0); // W_hh0 @ h0[t]
    }

    bar_wait(go, ep);   // h1[t] now visible

    // ---- phase e: head (row n = blk), spill-free chunked loads ----
    {
      const float* Ah = hWr + Hc * Bc + (kg * 32) * Bc + b;
      double hs = 0.0;
#pragma unroll 1
      for (int c = 0; c < 2; ++c) {
        float av[16];
#pragma unroll
        for (int k = 0; k < 16; ++k) av[k] = Ah[(c * 16 + k) * Bc];
#pragma unroll
        for (int kk = 0; kk < 16; kk += 4) {
          float4 w = *(const float4*)(&whd[kg * 32 + c * 16] + kk);
          float pp =  av[kk + 0] * w.x;
          pp = fmaf(av[kk + 1], w.y, pp);
          pp = fmaf(av[kk + 2], w.z, pp);
          pp = fmaf(av[kk + 3], w.w, pp);
          hs += (double)pp;
        }
      }
      pbuf[kg * 64 + b] = (float)hs;
    }
    __syncthreads();
    if (tid < 64) {
      double s = bembs;
#pragma unroll
      for (int pl = 0; pl < NWAVE; ++pl) s += (double)pbuf[pl * 64 + b];
      float o = (float)tanh(s);
      outT[blk * Bc + b] = o;                          // feedback buffer [NOUT][B]
      out[((size_t)b * Tc + t) * NOUTc + blk] = o;     // final output [B,T,NOUT]
    }
    if (upn) {
      bar_arrive(grp, root, go, blk, ++ep);            // publish out[t]
      bar_wait(go, ep);
    } else if (t + 1 < Tc) {
      __syncthreads();                                 // pbuf reuse guard
    }
  }
}

extern "C" void kernel_launch(void* const* d_in, const int* in_sizes, int n_in,
                              void* d_out, int out_size, void* d_ws, size_t ws_size,
                              hipStream_t stream) {
  const float* x    = (const float*)d_in[0];
  const float* h0   = (const float*)d_in[1];
  const float* c0   = (const float*)d_in[2];
  const float* Wih0 = (const float*)d_in[3];
  const float* Wih1 = (const float*)d_in[4];
  const float* Whh  = (const float*)d_in[5];
  const float* bih  = (const float*)d_in[6];
  const float* bhh  = (const float*)d_in[7];
  const float* Wemb = (const float*)d_in[8];
  const float* bemb = (const float*)d_in[9];
  const unsigned char* uprev = (const unsigned char*)d_in[10];
  float* out = (float*)d_out;
  float* ws  = (float*)d_ws;

  // zero the barrier control region (first 4 KiB) every call (inside graph)
  hipMemsetAsync(d_ws, 0, 4096, stream);

  void* args[] = {(void*)&x, (void*)&h0, (void*)&c0, (void*)&Wih0, (void*)&Wih1,
                  (void*)&Whh, (void*)&bih, (void*)&bhh, (void*)&Wemb, (void*)&bemb,
                  (void*)&uprev, (void*)&out, (void*)&ws};
  hipLaunchCooperativeKernel((void*)lstm_seq_kernel, dim3(NBLK), dim3(NTHR),
                             args, 0, stream);
}

// Round 11
// 12800.890 us; speedup vs baseline: 4.3001x; 1.3016x over previous
//
#include <hip/hip_runtime.h>

// Problem constants
#define Bc   64
#define Tc   512
#define NINc 256
#define Hc   512
#define NOUTc 256
#define NBLK 256
#define NTHR 1024
#define NWAVE 16
#define GSZ  32      // blocks per barrier group
#define NGRP 8       // groups

__device__ __forceinline__ double dsig(double x) { return 1.0 / (1.0 + exp(-x)); }

// ---- sc1 data plane: relaxed agent atomics bypass L1/L2, meet at MALL ----
__device__ __forceinline__ float ldg1(const float* p) {
  return __hip_atomic_load(p, __ATOMIC_RELAXED, __HIP_MEMORY_SCOPE_AGENT);
}
__device__ __forceinline__ void stg1(float* p, float v) {
  __hip_atomic_store(p, v, __ATOMIC_RELAXED, __HIP_MEMORY_SCOPE_AGENT);
}

// ---- flat fence-free grid barrier ----
// All cross-block data moves sc1 (already at coherence point) => no wbl2/inv ever.
// arrive: drain own vmem (sc1 stores ACKed at MALL), one relaxed RMW per block.
__device__ __forceinline__ void bar_arrive(unsigned* __restrict__ grp, int blk, unsigned ep) {
  asm volatile("s_waitcnt vmcnt(0)" ::: "memory");
  __syncthreads();
  if (threadIdx.x == 0)
    __hip_atomic_fetch_add(&grp[(blk >> 5) * 32], 1u,
                           __ATOMIC_RELAXED, __HIP_MEMORY_SCOPE_AGENT);
}
// wait: lanes 0..7 of wave0 poll the 8 group counters in parallel.
__device__ __forceinline__ void bar_wait(unsigned* __restrict__ grp, unsigned ep) {
  if (threadIdx.x < 64) {
    const unsigned tgt = ep * GSZ;
    for (;;) {
      bool ok = true;
      if (threadIdx.x < NGRP)
        ok = (__hip_atomic_load(&grp[threadIdx.x * 32], __ATOMIC_RELAXED,
                                __HIP_MEMORY_SCOPE_AGENT) >= tgt);
      if (__all(ok)) break;
      __builtin_amdgcn_s_sleep(1);
    }
  }
  __syncthreads();
  asm volatile("" ::: "memory");
}

// ---- fused CD: one sc1 activation stream feeds TWO 8-row weight blocks ----
// (W1 -> acc1 = W_ih1 @ h0[t];  W0 -> acc0 = W_hh0 @ h0[t] for step t+1)
template<int NK>
__device__ __forceinline__ void dot_cd(const float* __restrict__ A,
                                       const float* __restrict__ W1, const int ws1,
                                       double* __restrict__ acc1,
                                       const float* __restrict__ W0, const int ws0,
                                       double* __restrict__ acc0) {
#pragma unroll 1
  for (int c = 0; c < NK / 8; ++c) {
    float av[8];
#pragma unroll
    for (int k = 0; k < 8; ++k) av[k] = ldg1(A + (c * 8 + k) * Bc);
#pragma unroll
    for (int kk = 0; kk < 8; kk += 4) {
#pragma unroll
      for (int r = 0; r < 8; ++r) {
        float4 w = *(const float4*)(W1 + r * ws1 + c * 8 + kk);
        float p =  av[kk + 0] * w.x;
        p = fmaf(av[kk + 1], w.y, p);
        p = fmaf(av[kk + 2], w.z, p);
        p = fmaf(av[kk + 3], w.w, p);
        acc1[r] += (double)p;
      }
#pragma unroll
      for (int r = 0; r < 8; ++r) {
        float4 w = *(const float4*)(W0 + r * ws0 + c * 8 + kk);
        float p =  av[kk + 0] * w.x;
        p = fmaf(av[kk + 1], w.y, p);
        p = fmaf(av[kk + 2], w.z, p);
        p = fmaf(av[kk + 3], w.w, p);
        acc0[r] += (double)p;
      }
    }
  }
}

// ---- fused EB: one sc1 h1[t] stream feeds W_hh1 (acc1, for t+1) AND head row ----
template<int NK>
__device__ __forceinline__ void dot_eb(const float* __restrict__ A,
                                       const float* __restrict__ W1, const int ws1,
                                       double* __restrict__ acc1,
                                       const float* __restrict__ Wh,
                                       double* __restrict__ hs) {
#pragma unroll 1
  for (int c = 0; c < NK / 8; ++c) {
    float av[8];
#pragma unroll
    for (int k = 0; k < 8; ++k) av[k] = ldg1(A + (c * 8 + k) * Bc);
#pragma unroll
    for (int kk = 0; kk < 8; kk += 4) {
#pragma unroll
      for (int r = 0; r < 8; ++r) {
        float4 w = *(const float4*)(W1 + r * ws1 + c * 8 + kk);
        float p =  av[kk + 0] * w.x;
        p = fmaf(av[kk + 1], w.y, p);
        p = fmaf(av[kk + 2], w.z, p);
        p = fmaf(av[kk + 3], w.w, p);
        acc1[r] += (double)p;
      }
      float4 w = *(const float4*)(Wh + c * 8 + kk);
      float pp =  av[kk + 0] * w.x;
      pp = fmaf(av[kk + 1], w.y, pp);
      pp = fmaf(av[kk + 2], w.z, pp);
      pp = fmaf(av[kk + 3], w.w, pp);
      *hs += (double)pp;
    }
  }
}

// ---- single-acc sc1 dot (pre-loop init, feedback) ----
template<int NK>
__device__ __forceinline__ void dot8_a(const float* __restrict__ A,
                                       const float* __restrict__ W,
                                       const int wstride,
                                       double* __restrict__ acc) {
#pragma unroll 1
  for (int c = 0; c < NK / 8; ++c) {
    float av[8];
#pragma unroll
    for (int k = 0; k < 8; ++k) av[k] = ldg1(A + (c * 8 + k) * Bc);
#pragma unroll
    for (int kk = 0; kk < 8; kk += 4) {
#pragma unroll
      for (int r = 0; r < 8; ++r) {
        float4 w = *(const float4*)(W + r * wstride + c * 8 + kk);
        float p =  av[kk + 0] * w.x;
        p = fmaf(av[kk + 1], w.y, p);
        p = fmaf(av[kk + 2], w.z, p);
        p = fmaf(av[kk + 3], w.w, p);
        acc[r] += (double)p;
      }
    }
  }
}

// A contiguous (raw x row, normal cached — read-only, never invalidated now)
template<int NK>
__device__ __forceinline__ void dot8_x(const float* __restrict__ A,
                                       const float* __restrict__ W,
                                       const int wstride,
                                       double* __restrict__ acc) {
#pragma unroll
  for (int kk = 0; kk < NK; kk += 4) {
    float4 av = *(const float4*)(A + kk);
#pragma unroll
    for (int r = 0; r < 8; ++r) {
      float4 w = *(const float4*)(W + r * wstride + kk);
      float p =  av.x * w.x;
      p = fmaf(av.y, w.y, p);
      p = fmaf(av.z, w.z, p);
      p = fmaf(av.w, w.w, p);
      acc[r] += (double)p;
    }
  }
}

__device__ __forceinline__ void write_plane(float* __restrict__ pb,
                                            const double* __restrict__ acc,
                                            int kg, int b) {
#pragma unroll
  for (int r = 0; r < 8; ++r) pb[(kg * 8 + r) * 64 + b] = (float)acc[r];
}

__device__ __forceinline__ double sum_planes(const float* __restrict__ pb,
                                             int r, int b) {
  double s = 0.0;
#pragma unroll
  for (int p = 0; p < NWAVE; ++p) s += (double)pb[(p * 8 + r) * 64 + b];
  return s;
}

__device__ __forceinline__ float lstm_cell(const float* __restrict__ pb,
                                           const double* __restrict__ bias,
                                           int r0, int b, double* c) {
  double gi = sum_planes(pb, r0 + 0, b) + bias[r0 + 0];
  double gf = sum_planes(pb, r0 + 1, b) + bias[r0 + 1];
  double gg = sum_planes(pb, r0 + 2, b) + bias[r0 + 2];
  double go = sum_planes(pb, r0 + 3, b) + bias[r0 + 3];
  double cn = dsig(gf) * (*c) + dsig(gi) * tanh(gg);
  *c = cn;
  return (float)(dsig(go) * tanh(cn));
}

extern "C" __global__ __launch_bounds__(NTHR, 4)
void lstm_seq_kernel(const float* __restrict__ x,      // [B,T,NIN]
                     const float* __restrict__ h0in,   // [L,B,H]
                     const float* __restrict__ c0in,   // [L,B,H]
                     const float* __restrict__ Wih0,   // [4H,NIN]
                     const float* __restrict__ Wih1,   // [4H,H]
                     const float* __restrict__ Whh,    // [L,4H,H]
                     const float* __restrict__ bih,    // [L,4H]
                     const float* __restrict__ bhh,    // [L,4H]
                     const float* __restrict__ Wemb,   // [NOUT,H]
                     const float* __restrict__ bemb,   // [NOUT]
                     const unsigned char* __restrict__ uprev, // [T] bool (or int32)
                     float* __restrict__ out,          // [B,T,NOUT]
                     float* __restrict__ ws) {
  __shared__ __align__(16) float wl0[8 * 768];    // [r][ W_ih0(256) | W_hh0(512) ]
  __shared__ __align__(16) float wl1[8 * 1024];   // [r][ W_ih1(512) | W_hh1(512) ]
  __shared__ __align__(16) float whd[512];        // W_emb row `blk`
  __shared__ __align__(16) float pbuf[NWAVE * 8 * 64];
  __shared__ double biasesD[2][8];
  __shared__ double bembs;
  __shared__ int up_mode;

  const int tid = threadIdx.x;
  const int blk = blockIdx.x;
  const int b   = tid & 63;
  const int kg  = tid >> 6;   // wave index = K-group (0..15)
  const int j0  = blk * 2;

  // ---- workspace map (first 4 KiB control, zeroed by host memset) ----
  unsigned* grp = (unsigned*)ws;               // 8 counters, 128B apart
  float* h0p  = ws + 1024;                     // [H][B]  layer-0 h plane (single)
  float* h1p  = h0p + Hc * Bc;                 // [H][B]  layer-1 h plane
  float* outT = h1p + Hc * Bc;                 // [NOUT][B]

  // ---- detect use_prev dtype ----
  if (tid == 0) up_mode = 1;
  __syncthreads();
  {
    int bad = 0;
    for (int idx = tid; idx < Tc; idx += NTHR)
      if ((idx & 3) && uprev[idx]) bad = 1;
    if (bad) up_mode = 0;
  }

  // ---- load weights into LDS (cached reads; never invalidated) ----
  for (int r = 0; r < 8; ++r) {
    const int u = r >> 2, g = r & 3;
    const int row = g * Hc + (j0 + u);
    const float* sA = Wih0 + (size_t)row * NINc;
    const float* sB = Whh  + (size_t)row * Hc;
    const float* sC = Wih1 + (size_t)row * Hc;
    const float* sD = Whh  + (size_t)(4 * Hc) * Hc + (size_t)row * Hc;
    for (int i = tid; i < NINc; i += NTHR) wl0[r * 768 + i] = sA[i];
    for (int i = tid; i < Hc;   i += NTHR) wl0[r * 768 + NINc + i] = sB[i];
    for (int i = tid; i < Hc;   i += NTHR) wl1[r * 1024 + i] = sC[i];
    for (int i = tid; i < Hc;   i += NTHR) wl1[r * 1024 + Hc + i] = sD[i];
    if (tid == 0) {
      biasesD[0][r] = (double)bih[row] + (double)bhh[row];
      biasesD[1][r] = (double)bih[4 * Hc + row] + (double)bhh[4 * Hc + row];
    }
  }
  for (int i = tid; i < Hc; i += NTHR) whd[i] = Wemb[(size_t)blk * Hc + i];
  if (tid == 0) bembs = (double)bemb[blk];

  // ---- init h planes transposed to [H][B]; sc1 stores ----
  for (int idx = blk * NTHR + tid; idx < 2 * Hc * Bc; idx += NBLK * NTHR) {
    const int l   = idx / (Hc * Bc);
    const int rem = idx - l * (Hc * Bc);
    const int j   = rem >> 6;
    const int bb  = rem & 63;
    stg1((l ? h1p : h0p) + rem, h0in[((size_t)l * Bc + bb) * Hc + j]);
  }

  // ---- cell state (f64) in registers of threads 0..127 ----
  double c0r = 0.0, c1r = 0.0;
  const int cu = tid >> 6;
  if (tid < 128) {
    const int j = j0 + cu;
    c0r = (double)c0in[((size_t)0 * Bc + b) * Hc + j];
    c1r = (double)c0in[((size_t)1 * Bc + b) * Hc + j];
  }
  __syncthreads();
  const int upm = up_mode;
  const int* uprev32 = (const int*)uprev;
#define UPAT(tt) (upm ? (uprev32[tt] != 0) : (uprev[tt] != 0))

  unsigned ep = 0;
  bar_arrive(grp, blk, ++ep);   // publish h-plane init
  bar_wait(grp, ep);

  // ---- pre-loop: accL0 = W_ih0@x[0] + W_hh0@h0init; accL1 = W_hh1@h1init ----
  double accL0[8], accL1[8];
#pragma unroll
  for (int r = 0; r < 8; ++r) { accL0[r] = 0.0; accL1[r] = 0.0; }
  dot8_x<16>(x + ((size_t)b * Tc + 0) * NINc + kg * 16, &wl0[kg * 16], 768, accL0);
  dot8_a<32>(h0p + (kg * 32) * Bc + b, &wl0[NINc + kg * 32], 768, accL0);
  dot8_a<32>(h1p + (kg * 32) * Bc + b, &wl1[Hc + kg * 32], 1024, accL1);

  for (int t = 0; t < Tc; ++t) {
    const bool upn = (t + 1 < Tc) && UPAT(t + 1);

    // ---- 1. feedback part of L0[t] (only when scheduled sampling) ----
    if (t > 0 && UPAT(t))
      dot8_a<16>(outT + (kg * 16) * Bc + b, &wl0[kg * 16], 768, accL0);

    // ---- 2. L0 cell; publish h0[t] (sc1) ----
    write_plane(pbuf, accL0, kg, b);
    __syncthreads();
    if (tid < 128) {
      float hn = lstm_cell(pbuf, biasesD[0], cu * 4, b, &c0r);
      stg1(&h0p[(j0 + cu) * Bc + b], hn);
    }
#pragma unroll
    for (int r = 0; r < 8; ++r) accL0[r] = 0.0;
    bar_arrive(grp, blk, ++ep);

    // ---- 3. hidden behind bar1: x[t+1] part of L0[t+1] (cached) ----
    if (t + 1 < Tc && !upn)
      dot8_x<16>(x + ((size_t)b * Tc + (t + 1)) * NINc + kg * 16, &wl0[kg * 16], 768, accL0);

    bar_wait(grp, ep);   // h0[t] visible

    // ---- 5. fused CD: one h0[t] stream -> accL1 (W_ih1) + accL0 (W_hh0, t+1) ----
    dot_cd<32>(h0p + (kg * 32) * Bc + b,
               &wl1[kg * 32], 1024, accL1,
               &wl0[NINc + kg * 32], 768, accL0);

    // ---- 6. L1 cell; publish h1[t] (sc1) ----
    write_plane(pbuf, accL1, kg, b);
    __syncthreads();
    if (tid < 128) {
      float hn = lstm_cell(pbuf, biasesD[1], cu * 4, b, &c1r);
      stg1(&h1p[(j0 + cu) * Bc + b], hn);
    }
#pragma unroll
    for (int r = 0; r < 8; ++r) accL1[r] = 0.0;
    bar_arrive(grp, blk, ++ep);
    bar_wait(grp, ep);   // h1[t] visible

    // ---- 8. fused EB: one h1[t] stream -> head partial + accL1 (W_hh1, t+1) ----
    {
      double hs = 0.0;
      dot_eb<32>(h1p + (kg * 32) * Bc + b,
                 &wl1[Hc + kg * 32], 1024, accL1,
                 &whd[kg * 32], &hs);
      pbuf[kg * 64 + b] = (float)hs;
    }
    __syncthreads();

    // ---- 9. head finish; out + feedback publish ----
    if (tid < 64) {
      double s = bembs;
#pragma unroll
      for (int pl = 0; pl < NWAVE; ++pl) s += (double)pbuf[pl * 64 + b];
      float o = (float)tanh(s);
      stg1(&outT[blk * Bc + b], o);                    // feedback buffer [NOUT][B]
      out[((size_t)b * Tc + t) * NOUTc + blk] = o;     // final output [B,T,NOUT]
    }
    if (upn) {
      bar_arrive(grp, blk, ++ep);                      // publish out[t]
      bar_wait(grp, ep);
    } else if (t + 1 < Tc) {
      __syncthreads();                                 // pbuf reuse guard
    }
  }
}

extern "C" void kernel_launch(void* const* d_in, const int* in_sizes, int n_in,
                              void* d_out, int out_size, void* d_ws, size_t ws_size,
                              hipStream_t stream) {
  const float* x    = (const float*)d_in[0];
  const float* h0   = (const float*)d_in[1];
  const float* c0   = (const float*)d_in[2];
  const float* Wih0 = (const float*)d_in[3];
  const float* Wih1 = (const float*)d_in[4];
  const float* Whh  = (const float*)d_in[5];
  const float* bih  = (const float*)d_in[6];
  const float* bhh  = (const float*)d_in[7];
  const float* Wemb = (const float*)d_in[8];
  const float* bemb = (const float*)d_in[9];
  const unsigned char* uprev = (const unsigned char*)d_in[10];
  float* out = (float*)d_out;
  float* ws  = (float*)d_ws;

  // zero the barrier control region (first 4 KiB) every call (inside graph)
  hipMemsetAsync(d_ws, 0, 4096, stream);

  void* args[] = {(void*)&x, (void*)&h0, (void*)&c0, (void*)&Wih0, (void*)&Wih1,
                  (void*)&Whh, (void*)&bih, (void*)&bhh, (void*)&Wemb, (void*)&bemb,
                  (void*)&uprev, (void*)&out, (void*)&ws};
  hipLaunchCooperativeKernel((void*)lstm_seq_kernel, dim3(NBLK), dim3(NTHR),
                             args, 0, stream);
}